// Round 7
// baseline (395.199 us; speedup 1.0000x reference)
//
#include <hip/hip_runtime.h>

// SAGEConv x2 forward — global-CSR pipeline (no per-block sort).
// 7 dispatches, all graph-capture/replay safe:
//   prep        : zero deg/done, convert weights to bf16
//   hist        : per-node degree histogram (1 global atomicAdd / edge)
//   scanA       : per-256-tile exclusive scan of deg -> loc, tile sums;
//                 last-finishing block scans tile sums -> gbase
//   scanB       : rowptr[n] = cur[n] = gbase[tile] + loc[n]; rowptr[N] = E
//   place_gemm1 : placement blocks (pos = atomicAdd(cur[dst]); srcs[pos]=src)
//                 + MFMA gemm1 blocks in ONE grid (atomics hide under MFMA)
//   agg1_gemm2  : stage contiguous srcs segment -> LDS, fp8 gather-mean,
//                 h in LDS, in-block MFMA gemm2 -> hl/hr
//   agg2_final  : gather-mean over hl (bf16) + epilogue
// xl stored fp8 e4m3 (64 B/row): 16 edge-rows per gather wave-instruction.

constexpr int IN_DIM  = 128;
constexpr int HID     = 64;
constexpr int OUT_DIM = 32;
constexpr float SLOPE = 0.1f;
constexpr int NBKMAX  = 512;     // 256-node scan tiles (N <= 131072)
constexpr int LCAP    = 4096;    // lsrc capacity per 128-node block (mean ~2048)

typedef unsigned int uint32;
typedef unsigned short ushort16;
typedef unsigned char uchar8;
using floatx2 = __attribute__((ext_vector_type(2))) float;

__device__ inline float blo(uint32 u) { return __uint_as_float(u << 16); }
__device__ inline float bhi(uint32 u) { return __uint_as_float(u & 0xffff0000u); }
__device__ inline ushort16 f2b(float f) {
    uint32 u = __float_as_uint(f);
    u += 0x7fffu + ((u >> 16) & 1u);   // round-to-nearest-even
    return (ushort16)(u >> 16);
}
__device__ inline uint32 pack2(float lo, float hi) {
    return (uint32)f2b(lo) | ((uint32)f2b(hi) << 16);
}
__device__ inline float lrelu(float v) { return (v > 0.f) ? v : SLOPE * v; }
__device__ inline void addup(float* acc, uint4 u) {      // bf16 x8 (agg2)
    acc[0] += blo(u.x); acc[1] += bhi(u.x);
    acc[2] += blo(u.y); acc[3] += bhi(u.y);
    acc[4] += blo(u.z); acc[5] += bhi(u.z);
    acc[6] += blo(u.w); acc[7] += bhi(u.w);
}
__device__ inline uchar8 f2fp8(float f) {                // e4m3, RNE (HW)
    uint32 r = (uint32)__builtin_amdgcn_cvt_pk_fp8_f32(f, f, 0, false);
    return (uchar8)(r & 0xffu);
}
__device__ inline void addp4(float* acc, uint32 w) {     // fp8 x4 decode+add
    floatx2 a = __builtin_amdgcn_cvt_pk_f32_fp8((int)w, false);
    floatx2 b = __builtin_amdgcn_cvt_pk_f32_fp8((int)w, true);
    acc[0] += a[0]; acc[1] += a[1]; acc[2] += b[0]; acc[3] += b[1];
}
__device__ inline void addq(float* acc, uint4 u) {       // fp8 x16 (agg1)
    addp4(acc + 0, u.x); addp4(acc + 4, u.y);
    addp4(acc + 8, u.z); addp4(acc + 12, u.w);
}

// ---- prep: zero deg/done2 + convert weights to bf16 [col][k] layouts ----
__global__ __launch_bounds__(256) void prep_kernel(
    const float* __restrict__ Wl1, const float* __restrict__ Wr1,
    const float* __restrict__ Wl2, const float* __restrict__ Wr2,
    ushort16* __restrict__ Wb1, ushort16* __restrict__ Wb2,
    int* __restrict__ deg, int* __restrict__ done2, int N) {
    const int gid = blockIdx.x * 256 + threadIdx.x;
    const int stride = gridDim.x * 256;
    for (int i = gid; i < N + 2; i += stride) deg[i] = 0;
    if (gid == 0) *done2 = 0;
    for (int i = gid; i < 128 * 128; i += stride) {
        int c = i >> 7, k = i & 127;
        Wb1[i] = f2b((c < HID) ? Wl1[k * HID + c] : Wr1[k * HID + (c - HID)]);
    }
    for (int i = gid; i < 64 * 64; i += stride) {
        int c = i >> 6, k = i & 63;
        Wb2[i] = f2b((c < OUT_DIM) ? Wl2[k * OUT_DIM + c]
                                   : Wr2[k * OUT_DIM + (c - OUT_DIM)]);
    }
}

// ---- hist: per-node degree histogram ----
__global__ __launch_bounds__(256) void hist_kernel(
    const int* __restrict__ dst, int* __restrict__ deg, int E) {
    for (int e = blockIdx.x * 256 + threadIdx.x; e < E; e += gridDim.x * 256)
        atomicAdd(&deg[dst[e]], 1);
}

// ---- scanA: per-tile (256 nodes) exclusive scan; last block scans tiles ----
__global__ __launch_bounds__(256) void scanA_kernel(
    const int* __restrict__ deg, int* __restrict__ loc,
    int* __restrict__ bsum, int* __restrict__ gbase,
    int* __restrict__ done2, int N, int NBK) {
    __shared__ int s[256];
    __shared__ int flag;
    const int tid = threadIdx.x;
    const int n = blockIdx.x * 256 + tid;
    int v = (n < N) ? deg[n] : 0;
    s[tid] = v; __syncthreads();
    for (int off = 1; off < 256; off <<= 1) {
        int t = (tid >= off) ? s[tid - off] : 0;
        __syncthreads();
        s[tid] += t;
        __syncthreads();
    }
    if (n < N) loc[n] = s[tid] - v;                 // exclusive within tile
    if (tid == 255) bsum[blockIdx.x] = s[255];      // tile total
    __threadfence();
    if (tid == 0) flag = (atomicAdd(done2, 1) == NBK - 1) ? 1 : 0;
    __syncthreads();
    if (!flag) return;
    // last block: exclusive scan of tile sums (<= 512 tiles, pair trick)
    __threadfence();
    int v0 = (2 * tid     < NBK) ? atomicAdd(&bsum[2 * tid], 0)     : 0;
    int v1 = (2 * tid + 1 < NBK) ? atomicAdd(&bsum[2 * tid + 1], 0) : 0;
    s[tid] = v0 + v1; __syncthreads();
    for (int off = 1; off < 256; off <<= 1) {
        int t = (tid >= off) ? s[tid - off] : 0;
        __syncthreads();
        s[tid] += t;
        __syncthreads();
    }
    int base = s[tid] - (v0 + v1);
    if (2 * tid     < NBK) gbase[2 * tid]     = base;
    if (2 * tid + 1 < NBK) gbase[2 * tid + 1] = base + v0;
}

// ---- scanB: rowptr / cursor init ----
__global__ __launch_bounds__(256) void scanB_kernel(
    const int* __restrict__ loc, const int* __restrict__ gbase,
    int* __restrict__ rowptr, int* __restrict__ cur, int N, int E) {
    const int n = blockIdx.x * 256 + threadIdx.x;
    if (n < N) {
        int r = gbase[n >> 8] + loc[n];
        rowptr[n] = r;
        cur[n] = r;
    }
    if (n == 0) rowptr[N] = E;
}

// ---- fused: placement blocks (blockIdx < nplace) + MFMA gemm1 blocks ----
// placement: srcs[atomicAdd(&cur[dst])] = src (latency hides under gemm1).
// gemm1: x[N,128] @ Wb1 -> xl fp8[N,64], xr fp32[N,64]+b1. A-tile-only LDS.
__global__ __launch_bounds__(256) void place_gemm1_kernel(
    const float* __restrict__ x, const ushort16* __restrict__ Wb1,
    const float* __restrict__ b1,
    const int* __restrict__ src, const int* __restrict__ dst,
    int* __restrict__ cur, uint32* __restrict__ srcs,
    uchar8* __restrict__ xlb, float* __restrict__ xr,
    int N, int E, int nplace) {
    using frag = __attribute__((ext_vector_type(8))) short;
    using f32x4 = __attribute__((ext_vector_type(4))) float;
    constexpr int LDA = IN_DIM + 8;                 // 136 elems = 272 B
    __shared__ ushort16 Ash[64][LDA];               // 17.4 KB
    const int tid = threadIdx.x;
    if (blockIdx.x < nplace) {                      // ---- placement path ----
        const int stride = nplace * 256;
        for (int e = blockIdx.x * 256 + tid; e < E; e += stride) {
            int s = src[e];
            int d = dst[e];
            int pos = atomicAdd(&cur[d], 1);
            srcs[pos] = (uint32)s;
        }
        return;
    }
    // ---- gemm1 path ----
    const int n0 = (blockIdx.x - nplace) * 64;
    {
        const int lc = (tid & 31) * 4;
        for (int row = tid >> 5; row < 64; row += 8) {
            int node = n0 + row;
            float4 xv = (node < N)
                ? *reinterpret_cast<const float4*>(&x[(long)node * IN_DIM + lc])
                : float4{0.f, 0.f, 0.f, 0.f};
            ushort16 pk[4] = {f2b(xv.x), f2b(xv.y), f2b(xv.z), f2b(xv.w)};
            *reinterpret_cast<ushort2*>(&Ash[row][lc])     = ushort2{pk[0], pk[1]};
            *reinterpret_cast<ushort2*>(&Ash[row][lc + 2]) = ushort2{pk[2], pk[3]};
        }
    }
    __syncthreads();
    const int lane = tid & 63;
    const int m0   = (tid >> 6) * 16;
    const int mlo  = lane & 15;
    const int qk   = lane >> 4;
    frag Af[4];
#pragma unroll
    for (int kc = 0; kc < 4; ++kc)
        Af[kc] = *reinterpret_cast<const frag*>(&Ash[m0 + mlo][kc * 32 + qk * 8]);
#pragma unroll
    for (int ct = 0; ct < 8; ++ct) {
        f32x4 acc = {0.f, 0.f, 0.f, 0.f};
#pragma unroll
        for (int kc = 0; kc < 4; ++kc) {
            frag Bf = *reinterpret_cast<const frag*>(
                &Wb1[(ct * 16 + mlo) * 128 + kc * 32 + qk * 8]);
            acc = __builtin_amdgcn_mfma_f32_16x16x32_bf16(Af[kc], Bf, acc, 0, 0, 0);
        }
        const int col = ct * 16 + mlo;
#pragma unroll
        for (int r = 0; r < 4; ++r) {
            int node = n0 + m0 + qk * 4 + r;
            if (node < N) {
                if (col < HID) xlb[(long)node * HID + col] = f2fp8(acc[r]);
                else           xr[(long)node * HID + (col - HID)] = acc[r] + b1[col - HID];
            }
        }
    }
}

// ---- agg1 + gemm2 fused: block = 128 consecutive nodes, 512 threads ----
// Stage the block's contiguous srcs segment into LDS (one coalesced copy),
// gather-mean xl (fp8, 4 lanes/node x 16 B), h -> LDS bf16 tile, then the
// 128x64 @ 64x64 MFMA gemm2 in-block -> hl bf16[N,32], hr fp32[N,32]+b2.
__global__ __launch_bounds__(512) void agg1_gemm2_kernel(
    const uint32* __restrict__ srcs, const int* __restrict__ rowptr,
    const uint4* __restrict__ xlq, const float* __restrict__ xr,
    const ushort16* __restrict__ Wb2, const float* __restrict__ b2,
    ushort16* __restrict__ hl, float* __restrict__ hr, int N) {
    using frag = __attribute__((ext_vector_type(8))) short;
    using f32x4 = __attribute__((ext_vector_type(4))) float;
    constexpr int LDH = HID + 8;                    // 72 elems = 144 B
    __shared__ int rps[129];
    __shared__ int lsrc[LCAP];                      // 16 KB
    __shared__ ushort16 hsh[128][LDH];              // 18.4 KB bf16 h-tile
    const int tid = threadIdx.x;
    const int n0  = blockIdx.x * 128;
    if (tid < 129) {
        int nn = n0 + tid;
        rps[tid] = rowptr[nn < N ? nn : N];
    }
    __syncthreads();
    const int rp0 = rps[0];
    int sz = rps[128] - rp0;
    if (sz > LCAP) sz = LCAP;                       // 45-sigma safe (mean 2048)
    for (int i = tid; i < sz; i += 512)             // coalesced stage
        lsrc[i] = (int)srcs[rp0 + i];
    __syncthreads();
    // ---- gather: 4 lanes/node, 16 nodes/wave, 128 nodes ----
    const int lane = tid & 63;
    const int wid  = tid >> 6;
    const int li   = lane & 3;                      // 16-byte chunk of fp8 row
    {
        const int nlb = wid * 16 + (lane >> 2);     // 0..127 (row in hsh)
        const int n   = n0 + nlb;
        if (n < N) {
            const int lo0 = rps[nlb] - rp0;
            const int d   = rps[nlb + 1] - rps[nlb];
            float acc[16] = {};
            int j = 0;
            while (j + 8 <= d) {
                int i0[8];
#pragma unroll
                for (int t = 0; t < 8; ++t) i0[t] = lsrc[lo0 + j + t];
                uint4 u0[8];
#pragma unroll
                for (int t = 0; t < 8; ++t) u0[t] = xlq[(long)i0[t] * 4 + li];
#pragma unroll
                for (int t = 0; t < 8; ++t) addq(acc, u0[t]);
                j += 8;
            }
            if (j + 4 <= d) {
                int i1[4];
#pragma unroll
                for (int t = 0; t < 4; ++t) i1[t] = lsrc[lo0 + j + t];
                uint4 u1[4];
#pragma unroll
                for (int t = 0; t < 4; ++t) u1[t] = xlq[(long)i1[t] * 4 + li];
#pragma unroll
                for (int t = 0; t < 4; ++t) addq(acc, u1[t]);
                j += 4;
            }
            for (; j < d; ++j) {
                uint4 u = xlq[(long)lsrc[lo0 + j] * 4 + li];
                addq(acc, u);
            }
            const float dinv = (d > 0) ? (1.f / (float)d) : 1.f;
            const float* xrp = &xr[(long)n * HID + li * 16];
            float4 xa = *reinterpret_cast<const float4*>(xrp);
            float4 xb = *reinterpret_cast<const float4*>(xrp + 4);
            float4 xc = *reinterpret_cast<const float4*>(xrp + 8);
            float4 xd = *reinterpret_cast<const float4*>(xrp + 12);
            float hv[16];
            hv[0]  = fmaf(acc[0],  dinv, xa.x); hv[1]  = fmaf(acc[1],  dinv, xa.y);
            hv[2]  = fmaf(acc[2],  dinv, xa.z); hv[3]  = fmaf(acc[3],  dinv, xa.w);
            hv[4]  = fmaf(acc[4],  dinv, xb.x); hv[5]  = fmaf(acc[5],  dinv, xb.y);
            hv[6]  = fmaf(acc[6],  dinv, xb.z); hv[7]  = fmaf(acc[7],  dinv, xb.w);
            hv[8]  = fmaf(acc[8],  dinv, xc.x); hv[9]  = fmaf(acc[9],  dinv, xc.y);
            hv[10] = fmaf(acc[10], dinv, xc.z); hv[11] = fmaf(acc[11], dinv, xc.w);
            hv[12] = fmaf(acc[12], dinv, xd.x); hv[13] = fmaf(acc[13], dinv, xd.y);
            hv[14] = fmaf(acc[14], dinv, xd.z); hv[15] = fmaf(acc[15], dinv, xd.w);
#pragma unroll
            for (int t = 0; t < 16; ++t) hv[t] = lrelu(hv[t]);
            uint4 pk0, pk1;
            pk0.x = pack2(hv[0],  hv[1]);  pk0.y = pack2(hv[2],  hv[3]);
            pk0.z = pack2(hv[4],  hv[5]);  pk0.w = pack2(hv[6],  hv[7]);
            pk1.x = pack2(hv[8],  hv[9]);  pk1.y = pack2(hv[10], hv[11]);
            pk1.z = pack2(hv[12], hv[13]); pk1.w = pack2(hv[14], hv[15]);
            *reinterpret_cast<uint4*>(&hsh[nlb][li * 16])     = pk0;
            *reinterpret_cast<uint4*>(&hsh[nlb][li * 16 + 8]) = pk1;
        }
        // rows with n >= N stay uninitialized; their MFMA outputs are guarded.
    }
    __syncthreads();
    // ---- gemm2: hsh[128][64] bf16 @ Wb2 -> hl/hr (8 waves x 16 rows) ----
    const int m0  = wid * 16;
    const int mlo = lane & 15;
    const int qk  = lane >> 4;
    frag Af[2];
#pragma unroll
    for (int kc = 0; kc < 2; ++kc)
        Af[kc] = *reinterpret_cast<const frag*>(&hsh[m0 + mlo][kc * 32 + qk * 8]);
#pragma unroll
    for (int ct = 0; ct < 4; ++ct) {
        f32x4 acc = {0.f, 0.f, 0.f, 0.f};
#pragma unroll
        for (int kc = 0; kc < 2; ++kc) {
            frag Bf = *reinterpret_cast<const frag*>(
                &Wb2[(ct * 16 + mlo) * 64 + kc * 32 + qk * 8]);
            acc = __builtin_amdgcn_mfma_f32_16x16x32_bf16(Af[kc], Bf, acc, 0, 0, 0);
        }
        const int col = ct * 16 + mlo;
#pragma unroll
        for (int r = 0; r < 4; ++r) {
            int node = n0 + m0 + qk * 4 + r;
            if (node < N) {
                if (col < OUT_DIM) hl[(long)node * OUT_DIM + col] = f2b(acc[r]);
                else hr[(long)node * OUT_DIM + (col - OUT_DIM)] = acc[r] + b2[col - OUT_DIM];
            }
        }
    }
}

// ---- agg2: z = LR(mean-gather(hl) + hr) ----
// 4 lanes/node, 16 nodes/wave, 16 gathers in flight (R0-proven loops).
__global__ __launch_bounds__(256) void agg2_final_kernel(
    const int* __restrict__ rowptr, const int* __restrict__ deg,
    const uint32* __restrict__ srcs,
    const uint4* __restrict__ hlq, const float* __restrict__ hr,
    float* __restrict__ z, int N) {
    const int lane  = threadIdx.x & 63;
    const int li    = lane & 3;
    const int gbase = lane & 60;
    const int wave  = (blockIdx.x << 2) + (threadIdx.x >> 6);
    const int n     = wave * 16 + (lane >> 2);
    if (n >= N) return;
    const int rp = rowptr[n];
    const int d  = deg[n];
    float acc[8] = {};
    int j = 0;
    while (j + 16 <= d) {
        int sA = (int)srcs[rp + j + li];
        int sB = (int)srcs[rp + j + 4 + li];
        int sC = (int)srcs[rp + j + 8 + li];
        int sD = (int)srcs[rp + j + 12 + li];
        uint4 u[16];
#pragma unroll
        for (int t = 0; t < 4; ++t) u[t]      = hlq[(long)__shfl(sA, gbase + t) * 4 + li];
#pragma unroll
        for (int t = 0; t < 4; ++t) u[4 + t]  = hlq[(long)__shfl(sB, gbase + t) * 4 + li];
#pragma unroll
        for (int t = 0; t < 4; ++t) u[8 + t]  = hlq[(long)__shfl(sC, gbase + t) * 4 + li];
#pragma unroll
        for (int t = 0; t < 4; ++t) u[12 + t] = hlq[(long)__shfl(sD, gbase + t) * 4 + li];
#pragma unroll
        for (int t = 0; t < 16; ++t) addup(acc, u[t]);
        j += 16;
    }
    while (j + 4 <= d) {
        int sA = (int)srcs[rp + j + li];
        uint4 u[4];
#pragma unroll
        for (int t = 0; t < 4; ++t) u[t] = hlq[(long)__shfl(sA, gbase + t) * 4 + li];
#pragma unroll
        for (int t = 0; t < 4; ++t) addup(acc, u[t]);
        j += 4;
    }
    int r = d - j;                     // 0..3
    if (r > 0) {
        int sA = (int)srcs[rp + j + ((li < r) ? li : 0)];
#pragma unroll
        for (int t = 0; t < 3; ++t) {
            if (t < r) {
                uint4 u = hlq[(long)__shfl(sA, gbase + t) * 4 + li];
                addup(acc, u);
            }
        }
    }
    const float dinv = (d > 0) ? (1.f / (float)d) : 1.f;
    float4 hA = *reinterpret_cast<const float4*>(&hr[(long)n * OUT_DIM + 8 * li]);
    float4 hB = *reinterpret_cast<const float4*>(&hr[(long)n * OUT_DIM + 8 * li + 4]);
    float4 vA, vB;
    vA.x = lrelu(fmaf(acc[0], dinv, hA.x)); vA.y = lrelu(fmaf(acc[1], dinv, hA.y));
    vA.z = lrelu(fmaf(acc[2], dinv, hA.z)); vA.w = lrelu(fmaf(acc[3], dinv, hA.w));
    vB.x = lrelu(fmaf(acc[4], dinv, hB.x)); vB.y = lrelu(fmaf(acc[5], dinv, hB.y));
    vB.z = lrelu(fmaf(acc[6], dinv, hB.z)); vB.w = lrelu(fmaf(acc[7], dinv, hB.w));
    *reinterpret_cast<float4*>(&z[(long)n * OUT_DIM + 8 * li]) = vA;
    *reinterpret_cast<float4*>(&z[(long)n * OUT_DIM + 8 * li + 4]) = vB;
}

extern "C" void kernel_launch(void* const* d_in, const int* in_sizes, int n_in,
                              void* d_out, int out_size, void* d_ws, size_t ws_size,
                              hipStream_t stream) {
    const float* x   = (const float*)d_in[0];
    const int*   ei  = (const int*)d_in[1];
    const float* Wl1 = (const float*)d_in[2];
    const float* Wr1 = (const float*)d_in[3];
    const float* b1  = (const float*)d_in[4];
    const float* Wl2 = (const float*)d_in[5];
    const float* Wr2 = (const float*)d_in[6];
    const float* b2  = (const float*)d_in[7];

    const int N = in_sizes[0] / IN_DIM;
    const int E = in_sizes[1] / 2;
    const int* src = ei;
    const int* dst = ei + E;
    const int NBK = (N + 255) >> 8;          // scan tiles (<= 512)

    char* p = (char*)d_ws;
    int* deg      = (int*)p;           p += sizeof(int) * (N + 4);
    int* loc      = (int*)p;           p += sizeof(int) * (N + 4);
    int* rowptr   = (int*)p;           p += sizeof(int) * (N + 4);
    int* cur      = (int*)p;           p += sizeof(int) * (N + 4);
    int* bsum     = (int*)p;           p += sizeof(int) * NBKMAX;
    int* gbase    = (int*)p;           p += sizeof(int) * NBKMAX;
    int* done2    = (int*)p;           p += sizeof(int) * 4;
    uint32* srcs  = (uint32*)p;        p += sizeof(uint32) * ((size_t)E + 16);
    ushort16* Wb1 = (ushort16*)p;      p += sizeof(ushort16) * 128 * 128;
    ushort16* Wb2 = (ushort16*)p;      p += sizeof(ushort16) * 64 * 64;
    uchar8* xlb   = (uchar8*)p;        p += sizeof(uchar8) * ((size_t)N * HID + 64);
    float* xr     = (float*)p;         p += sizeof(float) * (size_t)N * HID;
    ushort16* hl  = (ushort16*)p;      p += sizeof(ushort16) * (size_t)N * OUT_DIM;
    float* hr     = (float*)p;         p += sizeof(float) * (size_t)N * OUT_DIM;

    const int ngemm  = (N + 63) / 64;
    const int nplace = 512;
    prep_kernel<<<96, 256, 0, stream>>>(Wl1, Wr1, Wl2, Wr2, Wb1, Wb2, deg, done2, N);
    hist_kernel<<<512, 256, 0, stream>>>(dst, deg, E);
    scanA_kernel<<<NBK, 256, 0, stream>>>(deg, loc, bsum, gbase, done2, N, NBK);
    scanB_kernel<<<NBK, 256, 0, stream>>>(loc, gbase, rowptr, cur, N, E);
    place_gemm1_kernel<<<nplace + ngemm, 256, 0, stream>>>(
        x, Wb1, b1, src, dst, cur, srcs, xlb, xr, N, E, nplace);
    agg1_gemm2_kernel<<<(N + 127) / 128, 512, 0, stream>>>(
        srcs, rowptr, (const uint4*)xlb, xr, Wb2, b2, hl, hr, N);
    agg2_final_kernel<<<(N + 63) / 64, 256, 0, stream>>>(rowptr, deg, srcs,
                                                         (const uint4*)hl, hr,
                                                         (float*)d_out, N);
}

// Round 8
// 278.735 us; speedup vs baseline: 1.4178x; 1.4178x over previous
//
#include <hip/hip_runtime.h>

// SAGEConv x2 forward. Edges bucket-partitioned by dst (256 nodes/bucket).
// Pipeline (5 dispatches, no host-side memset — graph-capture safe):
//   prep        : zero bhist/done, convert weights to bf16
//   hist_scan   : bucket histogram + (last block) padded prefix scan
//   gemm1_part  : MFMA gemm1 blocks + partition blocks in ONE grid (overlap)
//   agg1_gemm2  : LDS sort + gather-mean (R0-proven loops, bf16 xl) + h in LDS
//                 + in-block MFMA gemm2 -> hl fp8[N,32], hr fp32[N,32]+b2
//   agg2_final  : gather-mean over hl fp8 + epilogue
// hl stored fp8 e4m3: 3.2 MB total < 4 MB per-XCD L2 -> the layer-2 gather
// becomes L2-resident (~200cy) instead of L3 (~500+cy), and bytes halve.

constexpr int IN_DIM  = 128;
constexpr int HID     = 64;
constexpr int OUT_DIM = 32;
constexpr float SLOPE = 0.1f;
constexpr int NPB_SHIFT = 8;     // 256 nodes per bucket
constexpr int NBMAX = 512;       // max buckets (N <= 131072)
constexpr int CHUNK = 4096;      // edges per partition block
constexpr int SUBCAP = 4096;     // per-half-bucket edge capacity (avg ~2048)

typedef unsigned int uint32;
typedef unsigned short ushort16;
typedef unsigned char uchar8;
using floatx2 = __attribute__((ext_vector_type(2))) float;

__device__ inline float blo(uint32 u) { return __uint_as_float(u << 16); }
__device__ inline float bhi(uint32 u) { return __uint_as_float(u & 0xffff0000u); }
__device__ inline ushort16 f2b(float f) {
    uint32 u = __float_as_uint(f);
    u += 0x7fffu + ((u >> 16) & 1u);   // round-to-nearest-even
    return (ushort16)(u >> 16);
}
__device__ inline uint32 pack2(float lo, float hi) {
    return (uint32)f2b(lo) | ((uint32)f2b(hi) << 16);
}
__device__ inline float lrelu(float v) { return (v > 0.f) ? v : SLOPE * v; }
__device__ inline void addup(float* acc, uint4 u) {      // bf16 x8 (agg1)
    acc[0] += blo(u.x); acc[1] += bhi(u.x);
    acc[2] += blo(u.y); acc[3] += bhi(u.y);
    acc[4] += blo(u.z); acc[5] += bhi(u.z);
    acc[6] += blo(u.w); acc[7] += bhi(u.w);
}
__device__ inline uchar8 f2fp8(float f) {                // e4m3, RNE (HW)
    uint32 r = (uint32)__builtin_amdgcn_cvt_pk_fp8_f32(f, f, 0, false);
    return (uchar8)(r & 0xffu);
}
__device__ inline void addp4(float* acc, uint32 w) {     // fp8 x4 decode+add
    floatx2 a = __builtin_amdgcn_cvt_pk_f32_fp8((int)w, false);
    floatx2 b = __builtin_amdgcn_cvt_pk_f32_fp8((int)w, true);
    acc[0] += a[0]; acc[1] += a[1]; acc[2] += b[0]; acc[3] += b[1];
}
__device__ inline void addq8(float* acc, uint2 u) {      // fp8 x8 (agg2)
    addp4(acc + 0, u.x); addp4(acc + 4, u.y);
}

// ---- prep: zero bhist/done + convert weights to bf16 [col][k] layouts ----
__global__ __launch_bounds__(256) void prep_kernel(
    const float* __restrict__ Wl1, const float* __restrict__ Wr1,
    const float* __restrict__ Wl2, const float* __restrict__ Wr2,
    ushort16* __restrict__ Wb1, ushort16* __restrict__ Wb2,
    int* __restrict__ bhist, int* __restrict__ done) {
    const int gid = blockIdx.x * 256 + threadIdx.x;
    if (gid < NBMAX) bhist[gid] = 0;
    if (gid == NBMAX) *done = 0;
    for (int i = gid; i < 128 * 128; i += gridDim.x * 256) {
        int c = i >> 7, k = i & 127;
        Wb1[i] = f2b((c < HID) ? Wl1[k * HID + c] : Wr1[k * HID + (c - HID)]);
    }
    for (int i = gid; i < 64 * 64; i += gridDim.x * 256) {
        int c = i >> 6, k = i & 63;
        Wb2[i] = f2b((c < OUT_DIM) ? Wl2[k * OUT_DIM + c]
                                   : Wr2[k * OUT_DIM + (c - OUT_DIM)]);
    }
}

// ---- bucket histogram + fused scan (last-finishing block) ----
__global__ __launch_bounds__(256) void hist_scan_kernel(
    const int* __restrict__ dst, int* __restrict__ bhist,
    int* __restrict__ pbase, int* __restrict__ bcur,
    int* __restrict__ done, int E, int NB) {
    __shared__ int bh[NBMAX];
    __shared__ int s2[256];
    __shared__ int flag;
    const int tid = threadIdx.x;
    for (int i = tid; i < NBMAX; i += 256) bh[i] = 0;
    __syncthreads();
    for (int e = blockIdx.x * 256 + tid; e < E; e += gridDim.x * 256)
        atomicAdd(&bh[dst[e] >> NPB_SHIFT], 1);
    __syncthreads();
    for (int b = tid; b < NBMAX; b += 256)
        if (bh[b]) atomicAdd(&bhist[b], bh[b]);
    __threadfence();
    if (tid == 0) flag = (atomicAdd(done, 1) == (int)gridDim.x - 1) ? 1 : 0;
    __syncthreads();
    if (!flag) return;
    // last block: exclusive scan of 16-padded bucket sizes (512 bins, 256 thr)
    __threadfence();
    int v0 = atomicAdd(&bhist[2 * tid], 0);       // coherent-point read
    int v1 = atomicAdd(&bhist[2 * tid + 1], 0);
    int p0 = (v0 + 15) & ~15, p1 = (v1 + 15) & ~15;
    s2[tid] = p0 + p1; __syncthreads();
    for (int off = 1; off < 256; off <<= 1) {
        int b = (tid >= off) ? s2[tid - off] : 0;
        __syncthreads();
        s2[tid] += b;
        __syncthreads();
    }
    int base = s2[tid] - (p0 + p1);
    pbase[2 * tid]     = base;      bcur[2 * tid]     = base;
    pbase[2 * tid + 1] = base + p0; bcur[2 * tid + 1] = base + p0;
}

// ---- fused: partition blocks (blockIdx < npart) + MFMA gemm1 blocks ----
// partition: edges -> bucket regions of pairs[] (binary-search flush).
// gemm1: x[N,128] @ Wb1 -> xl bf16[N,64], xr fp32[N,64]+b1. A-tile-only LDS.
__global__ __launch_bounds__(256) void gemm1_part_kernel(
    const float* __restrict__ x, const ushort16* __restrict__ Wb1,
    const float* __restrict__ b1,
    const int* __restrict__ src, const int* __restrict__ dst,
    int* __restrict__ bcur, uint32* __restrict__ pairs,
    ushort16* __restrict__ xl, float* __restrict__ xr,
    int N, int E, int NB, int npart) {
    using frag = __attribute__((ext_vector_type(8))) short;
    using f32x4 = __attribute__((ext_vector_type(4))) float;
    constexpr int LDA = IN_DIM + 8;                 // 136 elems = 272 B
    __shared__ union {
        struct {
            int hist[NBMAX], loff[NBMAX], cur[NBMAX], gbase[NBMAX];
            int s[256];
            uint32 stage[CHUNK];
        } p;                                        // 25.6 KB
        ushort16 Ash[64][LDA];                      // 17.4 KB
    } sm;
    const int tid = threadIdx.x;
    if (blockIdx.x < npart) {                       // ---- partition path ----
        const int e0  = blockIdx.x * CHUNK;
        const int cnt = min(CHUNK, E - e0);
        for (int i = tid; i < NBMAX; i += 256) sm.p.hist[i] = 0;
        __syncthreads();
        int sreg[16], dreg[16];
#pragma unroll
        for (int k = 0; k < 16; ++k) {
            int i = tid + k * 256;
            if (i < cnt) {
                sreg[k] = src[e0 + i];
                dreg[k] = dst[e0 + i];
                atomicAdd(&sm.p.hist[dreg[k] >> NPB_SHIFT], 1);
            }
        }
        __syncthreads();
        int a0 = sm.p.hist[2 * tid], a1 = sm.p.hist[2 * tid + 1];
        sm.p.s[tid] = a0 + a1; __syncthreads();
        for (int off = 1; off < 256; off <<= 1) {
            int t = (tid >= off) ? sm.p.s[tid - off] : 0;
            __syncthreads();
            sm.p.s[tid] += t;
            __syncthreads();
        }
        int ex = sm.p.s[tid] - (a0 + a1);
        sm.p.loff[2 * tid] = ex;      sm.p.loff[2 * tid + 1] = ex + a0;
        sm.p.cur[2 * tid]  = ex;      sm.p.cur[2 * tid + 1]  = ex + a0;
        __syncthreads();
#pragma unroll
        for (int k = 0; k < 16; ++k) {
            int i = tid + k * 256;
            if (i < cnt) {
                int b = dreg[k] >> NPB_SHIFT;
                int pos = atomicAdd(&sm.p.cur[b], 1);
                sm.p.stage[pos] = (uint32)sreg[k] | ((uint32)(dreg[k] & 255) << 24);
            }
        }
        __syncthreads();
        for (int b = tid; b < NB; b += 256) {
            int cb = sm.p.hist[b];
            if (cb) sm.p.gbase[b] = atomicAdd(&bcur[b], cb);
        }
        __syncthreads();
        for (int i = tid; i < cnt; i += 256) {
            int lo = 0, hi = NB - 1;                // invariant: loff[lo] <= i
            while (lo < hi) {
                int mid = (lo + hi + 1) >> 1;
                if (sm.p.loff[mid] <= i) lo = mid; else hi = mid - 1;
            }
            pairs[sm.p.gbase[lo] + (i - sm.p.loff[lo])] = sm.p.stage[i];
        }
        return;
    }
    // ---- gemm1 path ----
    const int n0 = (blockIdx.x - npart) * 64;
    {
        const int lc = (tid & 31) * 4;
        for (int row = tid >> 5; row < 64; row += 8) {
            int node = n0 + row;
            float4 xv = (node < N)
                ? *reinterpret_cast<const float4*>(&x[(long)node * IN_DIM + lc])
                : float4{0.f, 0.f, 0.f, 0.f};
            ushort16 pk[4] = {f2b(xv.x), f2b(xv.y), f2b(xv.z), f2b(xv.w)};
            *reinterpret_cast<ushort2*>(&sm.Ash[row][lc])     = ushort2{pk[0], pk[1]};
            *reinterpret_cast<ushort2*>(&sm.Ash[row][lc + 2]) = ushort2{pk[2], pk[3]};
        }
    }
    __syncthreads();
    const int lane = tid & 63;
    const int m0   = (tid >> 6) * 16;
    const int mlo  = lane & 15;
    const int qk   = lane >> 4;
    frag Af[4];
#pragma unroll
    for (int kc = 0; kc < 4; ++kc)
        Af[kc] = *reinterpret_cast<const frag*>(&sm.Ash[m0 + mlo][kc * 32 + qk * 8]);
#pragma unroll
    for (int ct = 0; ct < 8; ++ct) {
        f32x4 acc = {0.f, 0.f, 0.f, 0.f};
#pragma unroll
        for (int kc = 0; kc < 4; ++kc) {
            frag Bf = *reinterpret_cast<const frag*>(
                &Wb1[(ct * 16 + mlo) * 128 + kc * 32 + qk * 8]);
            acc = __builtin_amdgcn_mfma_f32_16x16x32_bf16(Af[kc], Bf, acc, 0, 0, 0);
        }
        const int col = ct * 16 + mlo;
#pragma unroll
        for (int r = 0; r < 4; ++r) {
            int node = n0 + m0 + qk * 4 + r;
            if (node < N) {
                if (col < HID) xl[(long)node * HID + col] = f2b(acc[r]);
                else           xr[(long)node * HID + (col - HID)] = acc[r] + b1[col - HID];
            }
        }
    }
}

// ---- agg1 + fine-bin + gemm2 fused: block = half-bucket (128 nodes) ----
// Sorts the bucket's pairs in LDS, emits CSR (srcs/rowptr/deg) for agg2,
// computes h = LR(mean-gather(xl bf16) + xr) into an LDS bf16 tile (R0-proven
// gather: 8 lanes/node, 8 nodes/wave, 2 passes of 64, 16/8/tail batches),
// then the 128x64 @ 64x64 MFMA gemm2 -> hl fp8[N,32], hr fp32[N,32]+b2.
__global__ __launch_bounds__(512) void agg1_gemm2_kernel(
    const uint32* __restrict__ pairs, const int* __restrict__ bhist,
    const int* __restrict__ pbase,
    const uint4* __restrict__ xlq, const float* __restrict__ xr,
    const ushort16* __restrict__ Wb2, const float* __restrict__ b2,
    uint32* __restrict__ srcs, int* __restrict__ rowptr, int* __restrict__ degA,
    uchar8* __restrict__ hl8, float* __restrict__ hr, int N) {
    using frag = __attribute__((ext_vector_type(8))) short;
    using f32x4 = __attribute__((ext_vector_type(4))) float;
    constexpr int LDH = HID + 8;                    // 72 elems = 144 B
    __shared__ int hist[256], loff[256], cur[128];
    __shared__ int lsrc[SUBCAP];                    // 16 KB
    __shared__ ushort16 hsh[128][LDH];              // 18 KB bf16 h-tile
    const int tid  = threadIdx.x;
    const int bkt  = blockIdx.x >> 1;
    const int half = blockIdx.x & 1;
    const int n0   = bkt << NPB_SHIFT;
    const int base = pbase[bkt];
    const int sz   = bhist[bkt];
    if (tid < 256) hist[tid] = 0;
    __syncthreads();
    for (int i = tid; i < sz; i += 512)
        atomicAdd(&hist[pairs[base + i] >> 24], 1);
    __syncthreads();
    int v = (tid < 256) ? hist[tid] : 0;
    if (tid < 256) loff[tid] = v;
    __syncthreads();
    for (int off = 1; off < 256; off <<= 1) {
        int t = (tid >= off && tid < 256) ? loff[tid - off] : 0;
        __syncthreads();
        if (tid < 256) loff[tid] += t;
        __syncthreads();
    }
    if (tid < 256) loff[tid] -= v;                  // exclusive
    __syncthreads();
    if (half == 0 && tid < 256 && n0 + tid < N) {   // CSR for agg2
        rowptr[n0 + tid] = base + loff[tid];
        degA[n0 + tid]   = hist[tid];
    }
    const int hbase = loff[half << 7];
    const int hcnt  = (half ? sz : loff[128]) - hbase;
    if (tid < 128) cur[tid] = loff[(half << 7) + tid] - hbase;
    __syncthreads();
    for (int i = tid; i < sz; i += 512) {           // scatter my half into lsrc
        uint32 u = pairs[base + i];
        int dl = u >> 24;
        if ((dl >> 7) == half) {
            int pos = atomicAdd(&cur[dl & 127], 1);
            lsrc[pos] = (int)(u & 0xFFFFFFu);
        }
    }
    __syncthreads();
    for (int i = tid; i < hcnt; i += 512)           // coalesced CSR srcs
        srcs[base + hbase + i] = (uint32)lsrc[i];
    // ---- gather: 8 lanes/node, 8 nodes/wave, 2 passes of 64 nodes ----
    const int lane = tid & 63;
    const int wid  = tid >> 6;
    const int li   = lane & 7;
#pragma unroll
    for (int pass = 0; pass < 2; ++pass) {
        const int nll = pass * 64 + wid * 8 + (lane >> 3);  // row in hsh 0..127
        const int nl  = (half << 7) + nll;
        const int n   = n0 + nl;
        if (n >= N) continue;
        const int lo0 = loff[nl] - hbase;
        const int d   = hist[nl];
        float acc[8] = {};
        int j = 0;
        while (j + 16 <= d) {
            int i0[8], i1[8];
#pragma unroll
            for (int t = 0; t < 8; ++t) i0[t] = lsrc[lo0 + j + t];
#pragma unroll
            for (int t = 0; t < 8; ++t) i1[t] = lsrc[lo0 + j + 8 + t];
            uint4 u0[8], u1[8];
#pragma unroll
            for (int t = 0; t < 8; ++t) u0[t] = xlq[(long)i0[t] * 8 + li];
#pragma unroll
            for (int t = 0; t < 8; ++t) u1[t] = xlq[(long)i1[t] * 8 + li];
#pragma unroll
            for (int t = 0; t < 8; ++t) { addup(acc, u0[t]); addup(acc, u1[t]); }
            j += 16;
        }
        if (j + 8 <= d) {
            int i0[8];
#pragma unroll
            for (int t = 0; t < 8; ++t) i0[t] = lsrc[lo0 + j + t];
            uint4 u0[8];
#pragma unroll
            for (int t = 0; t < 8; ++t) u0[t] = xlq[(long)i0[t] * 8 + li];
#pragma unroll
            for (int t = 0; t < 8; ++t) addup(acc, u0[t]);
            j += 8;
        }
        for (; j < d; ++j) {
            uint4 u = xlq[(long)lsrc[lo0 + j] * 8 + li];
            addup(acc, u);
        }
        const float dinv = (d > 0) ? (1.f / (float)d) : 1.f;
        float4 xrA = *reinterpret_cast<const float4*>(&xr[(long)n * HID + 8 * li]);
        float4 xrB = *reinterpret_cast<const float4*>(&xr[(long)n * HID + 8 * li + 4]);
        float h[8];
        h[0] = fmaf(acc[0], dinv, xrA.x); h[1] = fmaf(acc[1], dinv, xrA.y);
        h[2] = fmaf(acc[2], dinv, xrA.z); h[3] = fmaf(acc[3], dinv, xrA.w);
        h[4] = fmaf(acc[4], dinv, xrB.x); h[5] = fmaf(acc[5], dinv, xrB.y);
        h[6] = fmaf(acc[6], dinv, xrB.z); h[7] = fmaf(acc[7], dinv, xrB.w);
#pragma unroll
        for (int t = 0; t < 8; ++t) h[t] = lrelu(h[t]);
        uint4 pk;
        pk.x = pack2(h[0], h[1]); pk.y = pack2(h[2], h[3]);
        pk.z = pack2(h[4], h[5]); pk.w = pack2(h[6], h[7]);
        *reinterpret_cast<uint4*>(&hsh[nll][li * 8]) = pk;
        // rows with n >= N stay uninitialized; their MFMA outputs are guarded.
    }
    __syncthreads();
    // ---- gemm2: hsh[128][64] bf16 @ Wb2 -> hl fp8 / hr (8 waves x 16 rows) --
    const int m0  = wid * 16;
    const int mlo = lane & 15;
    const int qk  = lane >> 4;
    frag Af[2];
#pragma unroll
    for (int kc = 0; kc < 2; ++kc)
        Af[kc] = *reinterpret_cast<const frag*>(&hsh[m0 + mlo][kc * 32 + qk * 8]);
#pragma unroll
    for (int ct = 0; ct < 4; ++ct) {
        f32x4 acc = {0.f, 0.f, 0.f, 0.f};
#pragma unroll
        for (int kc = 0; kc < 2; ++kc) {
            frag Bf = *reinterpret_cast<const frag*>(
                &Wb2[(ct * 16 + mlo) * 64 + kc * 32 + qk * 8]);
            acc = __builtin_amdgcn_mfma_f32_16x16x32_bf16(Af[kc], Bf, acc, 0, 0, 0);
        }
        const int col = ct * 16 + mlo;
#pragma unroll
        for (int r = 0; r < 4; ++r) {
            int node = n0 + (half << 7) + m0 + qk * 4 + r;
            if (node < N) {
                if (col < OUT_DIM) hl8[(long)node * OUT_DIM + col] = f2fp8(acc[r]);
                else hr[(long)node * OUT_DIM + (col - OUT_DIM)] = acc[r] + b2[col - OUT_DIM];
            }
        }
    }
}

// ---- agg2: z = LR(mean-gather(hl fp8) + hr) ----
// 4 lanes/node x 8B, 16 nodes/wave, 16 uint2 gathers in flight; hl total
// footprint 3.2 MB -> per-XCD-L2-resident.
__global__ __launch_bounds__(256) void agg2_final_kernel(
    const int* __restrict__ rowptr, const int* __restrict__ degA,
    const uint32* __restrict__ srcs,
    const uint2* __restrict__ hlq, const float* __restrict__ hr,
    float* __restrict__ z, int N) {
    const int lane  = threadIdx.x & 63;
    const int li    = lane & 3;
    const int gbase = lane & 60;
    const int wave  = (blockIdx.x << 2) + (threadIdx.x >> 6);
    const int n     = wave * 16 + (lane >> 2);
    if (n >= N) return;
    const int rp = rowptr[n];
    const int d  = degA[n];
    float acc[8] = {};
    int j = 0;
    while (j + 16 <= d) {
        int sA = (int)srcs[rp + j + li];
        int sB = (int)srcs[rp + j + 4 + li];
        int sC = (int)srcs[rp + j + 8 + li];
        int sD = (int)srcs[rp + j + 12 + li];
        uint2 u[16];
#pragma unroll
        for (int t = 0; t < 4; ++t) u[t]      = hlq[(long)__shfl(sA, gbase + t) * 4 + li];
#pragma unroll
        for (int t = 0; t < 4; ++t) u[4 + t]  = hlq[(long)__shfl(sB, gbase + t) * 4 + li];
#pragma unroll
        for (int t = 0; t < 4; ++t) u[8 + t]  = hlq[(long)__shfl(sC, gbase + t) * 4 + li];
#pragma unroll
        for (int t = 0; t < 4; ++t) u[12 + t] = hlq[(long)__shfl(sD, gbase + t) * 4 + li];
#pragma unroll
        for (int t = 0; t < 16; ++t) addq8(acc, u[t]);
        j += 16;
    }
    while (j + 4 <= d) {
        int sA = (int)srcs[rp + j + li];
        uint2 u[4];
#pragma unroll
        for (int t = 0; t < 4; ++t) u[t] = hlq[(long)__shfl(sA, gbase + t) * 4 + li];
#pragma unroll
        for (int t = 0; t < 4; ++t) addq8(acc, u[t]);
        j += 4;
    }
    int r = d - j;                     // 0..3
    if (r > 0) {
        int sA = (int)srcs[rp + j + ((li < r) ? li : 0)];
#pragma unroll
        for (int t = 0; t < 3; ++t) {
            if (t < r) {
                uint2 u = hlq[(long)__shfl(sA, gbase + t) * 4 + li];
                addq8(acc, u);
            }
        }
    }
    const float dinv = (d > 0) ? (1.f / (float)d) : 1.f;
    float4 hA = *reinterpret_cast<const float4*>(&hr[(long)n * OUT_DIM + 8 * li]);
    float4 hB = *reinterpret_cast<const float4*>(&hr[(long)n * OUT_DIM + 8 * li + 4]);
    float4 vA, vB;
    vA.x = lrelu(fmaf(acc[0], dinv, hA.x)); vA.y = lrelu(fmaf(acc[1], dinv, hA.y));
    vA.z = lrelu(fmaf(acc[2], dinv, hA.z)); vA.w = lrelu(fmaf(acc[3], dinv, hA.w));
    vB.x = lrelu(fmaf(acc[4], dinv, hB.x)); vB.y = lrelu(fmaf(acc[5], dinv, hB.y));
    vB.z = lrelu(fmaf(acc[6], dinv, hB.z)); vB.w = lrelu(fmaf(acc[7], dinv, hB.w));
    *reinterpret_cast<float4*>(&z[(long)n * OUT_DIM + 8 * li]) = vA;
    *reinterpret_cast<float4*>(&z[(long)n * OUT_DIM + 8 * li + 4]) = vB;
}

extern "C" void kernel_launch(void* const* d_in, const int* in_sizes, int n_in,
                              void* d_out, int out_size, void* d_ws, size_t ws_size,
                              hipStream_t stream) {
    const float* x   = (const float*)d_in[0];
    const int*   ei  = (const int*)d_in[1];
    const float* Wl1 = (const float*)d_in[2];
    const float* Wr1 = (const float*)d_in[3];
    const float* b1  = (const float*)d_in[4];
    const float* Wl2 = (const float*)d_in[5];
    const float* Wr2 = (const float*)d_in[6];
    const float* b2  = (const float*)d_in[7];

    const int N = in_sizes[0] / IN_DIM;
    const int E = in_sizes[1] / 2;
    const int* src = ei;
    const int* dst = ei + E;
    const int NB = (N + 255) >> NPB_SHIFT;   // buckets (<= 512)

    char* p = (char*)d_ws;
    int* bhist    = (int*)p;           p += sizeof(int) * NBMAX;
    int* done     = (int*)p;           p += sizeof(int) * 4;
    int* pbase    = (int*)p;           p += sizeof(int) * NBMAX;
    int* bcur     = (int*)p;           p += sizeof(int) * NBMAX;
    int* rowptr   = (int*)p;           p += sizeof(int) * (N + 4);
    int* degA     = (int*)p;           p += sizeof(int) * (N + 4);
    uint32* pairs = (uint32*)p;        p += sizeof(uint32) * ((size_t)E + 16 * NBMAX);
    uint32* srcs  = (uint32*)p;        p += sizeof(uint32) * ((size_t)E + 16 * NBMAX);
    ushort16* Wb1 = (ushort16*)p;      p += sizeof(ushort16) * 128 * 128;
    ushort16* Wb2 = (ushort16*)p;      p += sizeof(ushort16) * 64 * 64;
    ushort16* xl  = (ushort16*)p;      p += sizeof(ushort16) * (size_t)N * HID;
    float* xr     = (float*)p;         p += sizeof(float) * (size_t)N * HID;
    uchar8* hl8   = (uchar8*)p;        p += sizeof(uchar8) * ((size_t)N * OUT_DIM + 64);
    float* hr     = (float*)p;         p += sizeof(float) * (size_t)N * OUT_DIM;

    const int ngemm = (N + 63) / 64;
    const int npart = (E + CHUNK - 1) / CHUNK;
    prep_kernel<<<32, 256, 0, stream>>>(Wl1, Wr1, Wl2, Wr2, Wb1, Wb2, bhist, done);
    hist_scan_kernel<<<256, 256, 0, stream>>>(dst, bhist, pbase, bcur, done, E, NB);
    gemm1_part_kernel<<<npart + ngemm, 256, 0, stream>>>(
        x, Wb1, b1, src, dst, bcur, pairs, xl, xr, N, E, NB, npart);
    agg1_gemm2_kernel<<<NB * 2, 512, 0, stream>>>(pairs, bhist, pbase,
                                                  (const uint4*)xl, xr, Wb2, b2,
                                                  srcs, rowptr, degA, hl8, hr, N);
    agg2_final_kernel<<<(N + 63) / 64, 256, 0, stream>>>(rowptr, degA, srcs,
                                                         (const uint2*)hl8, hr,
                                                         (float*)d_out, N);
}

// Round 9
// 259.840 us; speedup vs baseline: 1.5209x; 1.0727x over previous
//
#include <hip/hip_runtime.h>

// SAGEConv x2 forward. Edges bucket-partitioned by dst (256 nodes/bucket).
// Pipeline (5 dispatches, no host-side memset — graph-capture safe):
//   prep        : zero bhist/done, convert weights to bf16
//   hist_scan   : bucket histogram + (last block) padded prefix scan
//   gemm1_part  : MFMA gemm1 + partition in ONE grid; xl bf16 / xr bf16
//                 stores staged through LDS -> coalesced uint4
//   agg1_gemm2  : LDS sort + gather-mean (R0 loops) + h in LDS + MFMA gemm2
//                 -> hl fp8 / hr bf16, staged through LDS -> coalesced uint4
//   agg2_final  : gather-mean over hl fp8 (3.2 MB, per-XCD-L2-resident) + epi
// All scattered epilogue stores go LDS->coalesced (R8's fp8 byte-scatter
// stores regressed agg1 by ~7 us). xr/hr in bf16 cut ~38 MB of traffic.

constexpr int IN_DIM  = 128;
constexpr int HID     = 64;
constexpr int OUT_DIM = 32;
constexpr float SLOPE = 0.1f;
constexpr int NPB_SHIFT = 8;     // 256 nodes per bucket
constexpr int NBMAX = 512;       // max buckets (N <= 131072)
constexpr int CHUNK = 4096;      // edges per partition block
constexpr int SUBCAP = 4096;     // per-half-bucket edge capacity (avg ~2048)

typedef unsigned int uint32;
typedef unsigned short ushort16;
typedef unsigned char uchar8;
using floatx2 = __attribute__((ext_vector_type(2))) float;

__device__ inline float blo(uint32 u) { return __uint_as_float(u << 16); }
__device__ inline float bhi(uint32 u) { return __uint_as_float(u & 0xffff0000u); }
__device__ inline ushort16 f2b(float f) {
    uint32 u = __float_as_uint(f);
    u += 0x7fffu + ((u >> 16) & 1u);   // round-to-nearest-even
    return (ushort16)(u >> 16);
}
__device__ inline uint32 pack2(float lo, float hi) {
    return (uint32)f2b(lo) | ((uint32)f2b(hi) << 16);
}
__device__ inline float lrelu(float v) { return (v > 0.f) ? v : SLOPE * v; }
__device__ inline void addup(float* acc, uint4 u) {      // bf16 x8 (agg1)
    acc[0] += blo(u.x); acc[1] += bhi(u.x);
    acc[2] += blo(u.y); acc[3] += bhi(u.y);
    acc[4] += blo(u.z); acc[5] += bhi(u.z);
    acc[6] += blo(u.w); acc[7] += bhi(u.w);
}
__device__ inline uchar8 f2fp8(float f) {                // e4m3, RNE (HW)
    uint32 r = (uint32)__builtin_amdgcn_cvt_pk_fp8_f32(f, f, 0, false);
    return (uchar8)(r & 0xffu);
}
__device__ inline void addp4(float* acc, uint32 w) {     // fp8 x4 decode+add
    floatx2 a = __builtin_amdgcn_cvt_pk_f32_fp8((int)w, false);
    floatx2 b = __builtin_amdgcn_cvt_pk_f32_fp8((int)w, true);
    acc[0] += a[0]; acc[1] += a[1]; acc[2] += b[0]; acc[3] += b[1];
}
__device__ inline void addq8(float* acc, uint2 u) {      // fp8 x8 (agg2)
    addp4(acc + 0, u.x); addp4(acc + 4, u.y);
}

// ---- prep: zero bhist/done + convert weights to bf16 [col][k] layouts ----
__global__ __launch_bounds__(256) void prep_kernel(
    const float* __restrict__ Wl1, const float* __restrict__ Wr1,
    const float* __restrict__ Wl2, const float* __restrict__ Wr2,
    ushort16* __restrict__ Wb1, ushort16* __restrict__ Wb2,
    int* __restrict__ bhist, int* __restrict__ done) {
    const int gid = blockIdx.x * 256 + threadIdx.x;
    if (gid < NBMAX) bhist[gid] = 0;
    if (gid == NBMAX) *done = 0;
    for (int i = gid; i < 128 * 128; i += gridDim.x * 256) {
        int c = i >> 7, k = i & 127;
        Wb1[i] = f2b((c < HID) ? Wl1[k * HID + c] : Wr1[k * HID + (c - HID)]);
    }
    for (int i = gid; i < 64 * 64; i += gridDim.x * 256) {
        int c = i >> 6, k = i & 63;
        Wb2[i] = f2b((c < OUT_DIM) ? Wl2[k * OUT_DIM + c]
                                   : Wr2[k * OUT_DIM + (c - OUT_DIM)]);
    }
}

// ---- bucket histogram + fused scan (last-finishing block) ----
__global__ __launch_bounds__(256) void hist_scan_kernel(
    const int* __restrict__ dst, int* __restrict__ bhist,
    int* __restrict__ pbase, int* __restrict__ bcur,
    int* __restrict__ done, int E, int NB) {
    __shared__ int bh[NBMAX];
    __shared__ int s2[256];
    __shared__ int flag;
    const int tid = threadIdx.x;
    for (int i = tid; i < NBMAX; i += 256) bh[i] = 0;
    __syncthreads();
    for (int e = blockIdx.x * 256 + tid; e < E; e += gridDim.x * 256)
        atomicAdd(&bh[dst[e] >> NPB_SHIFT], 1);
    __syncthreads();
    for (int b = tid; b < NBMAX; b += 256)
        if (bh[b]) atomicAdd(&bhist[b], bh[b]);
    __threadfence();
    if (tid == 0) flag = (atomicAdd(done, 1) == (int)gridDim.x - 1) ? 1 : 0;
    __syncthreads();
    if (!flag) return;
    // last block: exclusive scan of 16-padded bucket sizes (512 bins, 256 thr)
    __threadfence();
    int v0 = atomicAdd(&bhist[2 * tid], 0);       // coherent-point read
    int v1 = atomicAdd(&bhist[2 * tid + 1], 0);
    int p0 = (v0 + 15) & ~15, p1 = (v1 + 15) & ~15;
    s2[tid] = p0 + p1; __syncthreads();
    for (int off = 1; off < 256; off <<= 1) {
        int b = (tid >= off) ? s2[tid - off] : 0;
        __syncthreads();
        s2[tid] += b;
        __syncthreads();
    }
    int base = s2[tid] - (p0 + p1);
    pbase[2 * tid]     = base;      bcur[2 * tid]     = base;
    pbase[2 * tid + 1] = base + p0; bcur[2 * tid + 1] = base + p0;
}

// ---- fused: partition blocks (blockIdx < npart) + MFMA gemm1 blocks ----
// partition: edges -> bucket regions of pairs[] (binary-search flush).
// gemm1: x[N,128] @ Wb1 -> xl bf16[N,64], xr bf16[N,64]+b1 (LDS-staged
// coalesced stores). A-tile-only LDS.
__global__ __launch_bounds__(256) void gemm1_part_kernel(
    const float* __restrict__ x, const ushort16* __restrict__ Wb1,
    const float* __restrict__ b1,
    const int* __restrict__ src, const int* __restrict__ dst,
    int* __restrict__ bcur, uint32* __restrict__ pairs,
    ushort16* __restrict__ xl, ushort16* __restrict__ xr,
    int N, int E, int NB, int npart) {
    using frag = __attribute__((ext_vector_type(8))) short;
    using f32x4 = __attribute__((ext_vector_type(4))) float;
    constexpr int LDA = IN_DIM + 8;                 // 136 elems = 272 B
    __shared__ union {
        struct {
            int hist[NBMAX], loff[NBMAX], cur[NBMAX], gbase[NBMAX];
            int s[256];
            uint32 stage[CHUNK];
        } p;                                        // 25.6 KB
        ushort16 Ash[64][LDA];                      // 17.4 KB
        ushort16 xst[2][64][64];                    // 16 KB out-stage (xl, xr)
    } sm;
    const int tid = threadIdx.x;
    if (blockIdx.x < npart) {                       // ---- partition path ----
        const int e0  = blockIdx.x * CHUNK;
        const int cnt = min(CHUNK, E - e0);
        for (int i = tid; i < NBMAX; i += 256) sm.p.hist[i] = 0;
        __syncthreads();
        int sreg[16], dreg[16];
#pragma unroll
        for (int k = 0; k < 16; ++k) {
            int i = tid + k * 256;
            if (i < cnt) {
                sreg[k] = src[e0 + i];
                dreg[k] = dst[e0 + i];
                atomicAdd(&sm.p.hist[dreg[k] >> NPB_SHIFT], 1);
            }
        }
        __syncthreads();
        int a0 = sm.p.hist[2 * tid], a1 = sm.p.hist[2 * tid + 1];
        sm.p.s[tid] = a0 + a1; __syncthreads();
        for (int off = 1; off < 256; off <<= 1) {
            int t = (tid >= off) ? sm.p.s[tid - off] : 0;
            __syncthreads();
            sm.p.s[tid] += t;
            __syncthreads();
        }
        int ex = sm.p.s[tid] - (a0 + a1);
        sm.p.loff[2 * tid] = ex;      sm.p.loff[2 * tid + 1] = ex + a0;
        sm.p.cur[2 * tid]  = ex;      sm.p.cur[2 * tid + 1]  = ex + a0;
        __syncthreads();
#pragma unroll
        for (int k = 0; k < 16; ++k) {
            int i = tid + k * 256;
            if (i < cnt) {
                int b = dreg[k] >> NPB_SHIFT;
                int pos = atomicAdd(&sm.p.cur[b], 1);
                sm.p.stage[pos] = (uint32)sreg[k] | ((uint32)(dreg[k] & 255) << 24);
            }
        }
        __syncthreads();
        for (int b = tid; b < NB; b += 256) {
            int cb = sm.p.hist[b];
            if (cb) sm.p.gbase[b] = atomicAdd(&bcur[b], cb);
        }
        __syncthreads();
        for (int i = tid; i < cnt; i += 256) {
            int lo = 0, hi = NB - 1;                // invariant: loff[lo] <= i
            while (lo < hi) {
                int mid = (lo + hi + 1) >> 1;
                if (sm.p.loff[mid] <= i) lo = mid; else hi = mid - 1;
            }
            pairs[sm.p.gbase[lo] + (i - sm.p.loff[lo])] = sm.p.stage[i];
        }
        return;
    }
    // ---- gemm1 path ----
    const int n0 = (blockIdx.x - npart) * 64;
    {
        const int lc = (tid & 31) * 4;
        for (int row = tid >> 5; row < 64; row += 8) {
            int node = n0 + row;
            float4 xv = (node < N)
                ? *reinterpret_cast<const float4*>(&x[(long)node * IN_DIM + lc])
                : float4{0.f, 0.f, 0.f, 0.f};
            ushort16 pk[4] = {f2b(xv.x), f2b(xv.y), f2b(xv.z), f2b(xv.w)};
            *reinterpret_cast<ushort2*>(&sm.Ash[row][lc])     = ushort2{pk[0], pk[1]};
            *reinterpret_cast<ushort2*>(&sm.Ash[row][lc + 2]) = ushort2{pk[2], pk[3]};
        }
    }
    __syncthreads();
    const int lane = tid & 63;
    const int m0   = (tid >> 6) * 16;
    const int mlo  = lane & 15;
    const int qk   = lane >> 4;
    frag Af[4];
#pragma unroll
    for (int kc = 0; kc < 4; ++kc)
        Af[kc] = *reinterpret_cast<const frag*>(&sm.Ash[m0 + mlo][kc * 32 + qk * 8]);
    __syncthreads();                                // Ash dead -> xst reuse
#pragma unroll
    for (int ct = 0; ct < 8; ++ct) {
        f32x4 acc = {0.f, 0.f, 0.f, 0.f};
#pragma unroll
        for (int kc = 0; kc < 4; ++kc) {
            frag Bf = *reinterpret_cast<const frag*>(
                &Wb1[(ct * 16 + mlo) * 128 + kc * 32 + qk * 8]);
            acc = __builtin_amdgcn_mfma_f32_16x16x32_bf16(Af[kc], Bf, acc, 0, 0, 0);
        }
        const int col = ct * 16 + mlo;
#pragma unroll
        for (int r = 0; r < 4; ++r) {
            int row = m0 + qk * 4 + r;
            if (col < HID) sm.xst[0][row][col] = f2b(acc[r]);
            else           sm.xst[1][row][col - HID] = f2b(acc[r] + b1[col - HID]);
        }
    }
    __syncthreads();
    // coalesced bulk store: 64 rows x 8 uint4 each for xl and xr
    for (int idx = tid; idx < 64 * 8; idx += 256) {
        int row = idx >> 3, ch = idx & 7;
        int node = n0 + row;
        if (node < N) {
            reinterpret_cast<uint4*>(xl)[(long)node * 8 + ch] =
                reinterpret_cast<const uint4*>(&sm.xst[0][0][0])[idx];
            reinterpret_cast<uint4*>(xr)[(long)node * 8 + ch] =
                reinterpret_cast<const uint4*>(&sm.xst[1][0][0])[idx];
        }
    }
}

// ---- agg1 + fine-bin + gemm2 fused: block = half-bucket (128 nodes) ----
// Sorts the bucket's pairs in LDS, emits CSR (srcs/rowptr/deg) for agg2,
// computes h = LR(mean-gather(xl bf16) + xr bf16) into an LDS bf16 tile
// (R0-proven gather: 8 lanes/node, 2 passes, 16/8/tail), then the 128x64 @
// 64x64 MFMA gemm2 -> hl fp8 / hr bf16 staged in LDS, coalesced stores.
__global__ __launch_bounds__(512) void agg1_gemm2_kernel(
    const uint32* __restrict__ pairs, const int* __restrict__ bhist,
    const int* __restrict__ pbase,
    const uint4* __restrict__ xlq, const uint4* __restrict__ xrq,
    const ushort16* __restrict__ Wb2, const float* __restrict__ b2,
    uint32* __restrict__ srcs, int* __restrict__ rowptr, int* __restrict__ degA,
    uchar8* __restrict__ hl8, ushort16* __restrict__ hr, int N) {
    using frag = __attribute__((ext_vector_type(8))) short;
    using f32x4 = __attribute__((ext_vector_type(4))) float;
    constexpr int LDH = HID + 8;                    // 72 elems = 144 B
    __shared__ int hist[256], loff[256], cur[128];
    __shared__ int lsrc[SUBCAP];                    // 16 KB (reused as out-stage)
    __shared__ ushort16 hsh[128][LDH];              // 18 KB bf16 h-tile
    const int tid  = threadIdx.x;
    const int bkt  = blockIdx.x >> 1;
    const int half = blockIdx.x & 1;
    const int n0   = bkt << NPB_SHIFT;
    const int base = pbase[bkt];
    const int sz   = bhist[bkt];
    if (tid < 256) hist[tid] = 0;
    __syncthreads();
    for (int i = tid; i < sz; i += 512)
        atomicAdd(&hist[pairs[base + i] >> 24], 1);
    __syncthreads();
    int v = (tid < 256) ? hist[tid] : 0;
    if (tid < 256) loff[tid] = v;
    __syncthreads();
    for (int off = 1; off < 256; off <<= 1) {
        int t = (tid >= off && tid < 256) ? loff[tid - off] : 0;
        __syncthreads();
        if (tid < 256) loff[tid] += t;
        __syncthreads();
    }
    if (tid < 256) loff[tid] -= v;                  // exclusive
    __syncthreads();
    if (half == 0 && tid < 256 && n0 + tid < N) {   // CSR for agg2
        rowptr[n0 + tid] = base + loff[tid];
        degA[n0 + tid]   = hist[tid];
    }
    const int hbase = loff[half << 7];
    const int hcnt  = (half ? sz : loff[128]) - hbase;
    if (tid < 128) cur[tid] = loff[(half << 7) + tid] - hbase;
    __syncthreads();
    for (int i = tid; i < sz; i += 512) {           // scatter my half into lsrc
        uint32 u = pairs[base + i];
        int dl = u >> 24;
        if ((dl >> 7) == half) {
            int pos = atomicAdd(&cur[dl & 127], 1);
            lsrc[pos] = (int)(u & 0xFFFFFFu);
        }
    }
    __syncthreads();
    for (int i = tid; i < hcnt; i += 512)           // coalesced CSR srcs
        srcs[base + hbase + i] = (uint32)lsrc[i];
    // ---- gather: 8 lanes/node, 8 nodes/wave, 2 passes of 64 nodes ----
    const int lane = tid & 63;
    const int wid  = tid >> 6;
    const int li   = lane & 7;
#pragma unroll
    for (int pass = 0; pass < 2; ++pass) {
        const int nll = pass * 64 + wid * 8 + (lane >> 3);  // row in hsh 0..127
        const int nl  = (half << 7) + nll;
        const int n   = n0 + nl;
        if (n >= N) continue;
        const int lo0 = loff[nl] - hbase;
        const int d   = hist[nl];
        float acc[8] = {};
        int j = 0;
        while (j + 16 <= d) {
            int i0[8], i1[8];
#pragma unroll
            for (int t = 0; t < 8; ++t) i0[t] = lsrc[lo0 + j + t];
#pragma unroll
            for (int t = 0; t < 8; ++t) i1[t] = lsrc[lo0 + j + 8 + t];
            uint4 u0[8], u1[8];
#pragma unroll
            for (int t = 0; t < 8; ++t) u0[t] = xlq[(long)i0[t] * 8 + li];
#pragma unroll
            for (int t = 0; t < 8; ++t) u1[t] = xlq[(long)i1[t] * 8 + li];
#pragma unroll
            for (int t = 0; t < 8; ++t) { addup(acc, u0[t]); addup(acc, u1[t]); }
            j += 16;
        }
        if (j + 8 <= d) {
            int i0[8];
#pragma unroll
            for (int t = 0; t < 8; ++t) i0[t] = lsrc[lo0 + j + t];
            uint4 u0[8];
#pragma unroll
            for (int t = 0; t < 8; ++t) u0[t] = xlq[(long)i0[t] * 8 + li];
#pragma unroll
            for (int t = 0; t < 8; ++t) addup(acc, u0[t]);
            j += 8;
        }
        for (; j < d; ++j) {
            uint4 u = xlq[(long)lsrc[lo0 + j] * 8 + li];
            addup(acc, u);
        }
        const float dinv = (d > 0) ? (1.f / (float)d) : 1.f;
        uint4 xv = xrq[(long)n * 8 + li];           // 8 bf16 xr values
        float h[8];
        h[0] = fmaf(acc[0], dinv, blo(xv.x)); h[1] = fmaf(acc[1], dinv, bhi(xv.x));
        h[2] = fmaf(acc[2], dinv, blo(xv.y)); h[3] = fmaf(acc[3], dinv, bhi(xv.y));
        h[4] = fmaf(acc[4], dinv, blo(xv.z)); h[5] = fmaf(acc[5], dinv, bhi(xv.z));
        h[6] = fmaf(acc[6], dinv, blo(xv.w)); h[7] = fmaf(acc[7], dinv, bhi(xv.w));
#pragma unroll
        for (int t = 0; t < 8; ++t) h[t] = lrelu(h[t]);
        uint4 pk;
        pk.x = pack2(h[0], h[1]); pk.y = pack2(h[2], h[3]);
        pk.z = pack2(h[4], h[5]); pk.w = pack2(h[6], h[7]);
        *reinterpret_cast<uint4*>(&hsh[nll][li * 8]) = pk;
        // rows with n >= N stay uninitialized; their MFMA outputs are guarded.
    }
    __syncthreads();                                // lsrc dead -> out-stage
    // ---- gemm2: hsh[128][64] bf16 @ Wb2, stage hl fp8 + hr bf16 in LDS ----
    unsigned char* hl_st = reinterpret_cast<unsigned char*>(lsrc);       // 4 KB
    ushort16* hr_st = reinterpret_cast<ushort16*>(lsrc + 1024);          // 8 KB
    const int m0  = wid * 16;
    const int mlo = lane & 15;
    const int qk  = lane >> 4;
    frag Af[2];
#pragma unroll
    for (int kc = 0; kc < 2; ++kc)
        Af[kc] = *reinterpret_cast<const frag*>(&hsh[m0 + mlo][kc * 32 + qk * 8]);
#pragma unroll
    for (int ct = 0; ct < 4; ++ct) {
        f32x4 acc = {0.f, 0.f, 0.f, 0.f};
#pragma unroll
        for (int kc = 0; kc < 2; ++kc) {
            frag Bf = *reinterpret_cast<const frag*>(
                &Wb2[(ct * 16 + mlo) * 64 + kc * 32 + qk * 8]);
            acc = __builtin_amdgcn_mfma_f32_16x16x32_bf16(Af[kc], Bf, acc, 0, 0, 0);
        }
        const int col = ct * 16 + mlo;
#pragma unroll
        for (int r = 0; r < 4; ++r) {
            int row = m0 + qk * 4 + r;
            if (col < OUT_DIM) hl_st[row * 32 + col] = f2fp8(acc[r]);
            else hr_st[row * 32 + (col - OUT_DIM)] = f2b(acc[r] + b2[col - OUT_DIM]);
        }
    }
    __syncthreads();
    // coalesced bulk stores: hl 128x2 uint4, hr 128x4 uint4
    for (int idx = tid; idx < 128 * 2; idx += 512) {
        int row = idx >> 1, ch = idx & 1;
        int node = n0 + (half << 7) + row;
        if (node < N)
            reinterpret_cast<uint4*>(hl8)[(long)node * 2 + ch] =
                reinterpret_cast<const uint4*>(hl_st)[idx];
    }
    for (int idx = tid; idx < 128 * 4; idx += 512) {
        int row = idx >> 2, ch = idx & 3;
        int node = n0 + (half << 7) + row;
        if (node < N)
            reinterpret_cast<uint4*>(hr)[(long)node * 4 + ch] =
                reinterpret_cast<const uint4*>(hr_st)[idx];
    }
}

// ---- agg2: z = LR(mean-gather(hl fp8) + hr bf16) ----
// 4 lanes/node x 8B, 16 nodes/wave, 16 uint2 gathers in flight; hl total
// footprint 3.2 MB -> per-XCD-L2-resident.
__global__ __launch_bounds__(256) void agg2_final_kernel(
    const int* __restrict__ rowptr, const int* __restrict__ degA,
    const uint32* __restrict__ srcs,
    const uint2* __restrict__ hlq, const uint4* __restrict__ hrq,
    float* __restrict__ z, int N) {
    const int lane  = threadIdx.x & 63;
    const int li    = lane & 3;
    const int gbase = lane & 60;
    const int wave  = (blockIdx.x << 2) + (threadIdx.x >> 6);
    const int n     = wave * 16 + (lane >> 2);
    if (n >= N) return;
    const int rp = rowptr[n];
    const int d  = degA[n];
    float acc[8] = {};
    int j = 0;
    while (j + 16 <= d) {
        int sA = (int)srcs[rp + j + li];
        int sB = (int)srcs[rp + j + 4 + li];
        int sC = (int)srcs[rp + j + 8 + li];
        int sD = (int)srcs[rp + j + 12 + li];
        uint2 u[16];
#pragma unroll
        for (int t = 0; t < 4; ++t) u[t]      = hlq[(long)__shfl(sA, gbase + t) * 4 + li];
#pragma unroll
        for (int t = 0; t < 4; ++t) u[4 + t]  = hlq[(long)__shfl(sB, gbase + t) * 4 + li];
#pragma unroll
        for (int t = 0; t < 4; ++t) u[8 + t]  = hlq[(long)__shfl(sC, gbase + t) * 4 + li];
#pragma unroll
        for (int t = 0; t < 4; ++t) u[12 + t] = hlq[(long)__shfl(sD, gbase + t) * 4 + li];
#pragma unroll
        for (int t = 0; t < 16; ++t) addq8(acc, u[t]);
        j += 16;
    }
    while (j + 4 <= d) {
        int sA = (int)srcs[rp + j + li];
        uint2 u[4];
#pragma unroll
        for (int t = 0; t < 4; ++t) u[t] = hlq[(long)__shfl(sA, gbase + t) * 4 + li];
#pragma unroll
        for (int t = 0; t < 4; ++t) addq8(acc, u[t]);
        j += 4;
    }
    int r = d - j;                     // 0..3
    if (r > 0) {
        int sA = (int)srcs[rp + j + ((li < r) ? li : 0)];
#pragma unroll
        for (int t = 0; t < 3; ++t) {
            if (t < r) {
                uint2 u = hlq[(long)__shfl(sA, gbase + t) * 4 + li];
                addq8(acc, u);
            }
        }
    }
    const float dinv = (d > 0) ? (1.f / (float)d) : 1.f;
    uint4 hv = hrq[(long)n * 4 + li];               // 8 bf16 hr values
    float4 vA, vB;
    vA.x = lrelu(fmaf(acc[0], dinv, blo(hv.x))); vA.y = lrelu(fmaf(acc[1], dinv, bhi(hv.x)));
    vA.z = lrelu(fmaf(acc[2], dinv, blo(hv.y))); vA.w = lrelu(fmaf(acc[3], dinv, bhi(hv.y)));
    vB.x = lrelu(fmaf(acc[4], dinv, blo(hv.z))); vB.y = lrelu(fmaf(acc[5], dinv, bhi(hv.z)));
    vB.z = lrelu(fmaf(acc[6], dinv, blo(hv.w))); vB.w = lrelu(fmaf(acc[7], dinv, bhi(hv.w)));
    *reinterpret_cast<float4*>(&z[(long)n * OUT_DIM + 8 * li]) = vA;
    *reinterpret_cast<float4*>(&z[(long)n * OUT_DIM + 8 * li + 4]) = vB;
}

extern "C" void kernel_launch(void* const* d_in, const int* in_sizes, int n_in,
                              void* d_out, int out_size, void* d_ws, size_t ws_size,
                              hipStream_t stream) {
    const float* x   = (const float*)d_in[0];
    const int*   ei  = (const int*)d_in[1];
    const float* Wl1 = (const float*)d_in[2];
    const float* Wr1 = (const float*)d_in[3];
    const float* b1  = (const float*)d_in[4];
    const float* Wl2 = (const float*)d_in[5];
    const float* Wr2 = (const float*)d_in[6];
    const float* b2  = (const float*)d_in[7];

    const int N = in_sizes[0] / IN_DIM;
    const int E = in_sizes[1] / 2;
    const int* src = ei;
    const int* dst = ei + E;
    const int NB = (N + 255) >> NPB_SHIFT;   // buckets (<= 512)

    char* p = (char*)d_ws;
    int* bhist    = (int*)p;           p += sizeof(int) * NBMAX;
    int* done     = (int*)p;           p += sizeof(int) * 4;
    int* pbase    = (int*)p;           p += sizeof(int) * NBMAX;
    int* bcur     = (int*)p;           p += sizeof(int) * NBMAX;
    int* rowptr   = (int*)p;           p += sizeof(int) * (N + 4);
    int* degA     = (int*)p;           p += sizeof(int) * (N + 4);
    uint32* pairs = (uint32*)p;        p += sizeof(uint32) * ((size_t)E + 16 * NBMAX);
    uint32* srcs  = (uint32*)p;        p += sizeof(uint32) * ((size_t)E + 16 * NBMAX);
    ushort16* Wb1 = (ushort16*)p;      p += sizeof(ushort16) * 128 * 128;
    ushort16* Wb2 = (ushort16*)p;      p += sizeof(ushort16) * 64 * 64;
    ushort16* xl  = (ushort16*)p;      p += sizeof(ushort16) * (size_t)N * HID;
    ushort16* xr  = (ushort16*)p;      p += sizeof(ushort16) * ((size_t)N * HID + 8);
    uchar8* hl8   = (uchar8*)p;        p += sizeof(uchar8) * ((size_t)N * OUT_DIM + 64);
    ushort16* hr  = (ushort16*)p;      p += sizeof(ushort16) * ((size_t)N * OUT_DIM + 8);

    const int ngemm = (N + 63) / 64;
    const int npart = (E + CHUNK - 1) / CHUNK;
    prep_kernel<<<32, 256, 0, stream>>>(Wl1, Wr1, Wl2, Wr2, Wb1, Wb2, bhist, done);
    hist_scan_kernel<<<256, 256, 0, stream>>>(dst, bhist, pbase, bcur, done, E, NB);
    gemm1_part_kernel<<<npart + ngemm, 256, 0, stream>>>(
        x, Wb1, b1, src, dst, bcur, pairs, xl, xr, N, E, NB, npart);
    agg1_gemm2_kernel<<<NB * 2, 512, 0, stream>>>(pairs, bhist, pbase,
                                                  (const uint4*)xl, (const uint4*)xr,
                                                  Wb2, b2,
                                                  srcs, rowptr, degA, hl8, hr, N);
    agg2_final_kernel<<<(N + 63) / 64, 256, 0, stream>>>(rowptr, degA, srcs,
                                                         (const uint2*)hl8,
                                                         (const uint4*)hr,
                                                         (float*)d_out, N);
}